// Round 13
// baseline (209.152 us; speedup 1.0000x reference)
//
#include <hip/hip_runtime.h>
#include <hip/hip_bf16.h>

#define NB 8
#define BATCH 8192
#define DIM 4096

typedef __attribute__((ext_vector_type(8))) short bf16x8;
typedef __attribute__((ext_vector_type(4))) float f32x4;
typedef unsigned long long ull;

#define SWZ8(r) (((r) & 7) << 4)

__device__ __forceinline__ unsigned short f2bf(float f) {
    return __builtin_bit_cast(unsigned short, __float2bfloat16(f));
}

__device__ __forceinline__ ull pack4(f32x4 f) {
    return (ull)f2bf(f.x) | ((ull)f2bf(f.y) << 16)
         | ((ull)f2bf(f.z) << 32) | ((ull)f2bf(f.w) << 48);
}

__device__ __forceinline__ void gload16(const void* g, void* l) {
    __builtin_amdgcn_global_load_lds(
        (const __attribute__((address_space(1))) unsigned int*)g,
        (__attribute__((address_space(3))) unsigned int*)l, 16, 0, 0);
}

// ---------------- weight pack ----------------
// W f32 [nb][512 out][512 in] -> pk: per (nb, nt 0..3, kt 0..7) a 16 KB tile:
// byte addr within tile = c*128 + ((k*2) ^ SWZ8(c)),  c = out-col local 0..127,
// k = in 0..63. Pre-swizzled so gload_lds (linear) lands bank-friendly.
__global__ void pack_w(const float* __restrict__ W, unsigned char* __restrict__ pk) {
    int gid = blockIdx.x * 256 + threadIdx.x;    // 262144 = 8*4*8*128*8
    int kc = gid & 7;                            // k-chunk (8 elems)
    int c  = (gid >> 3) & 127;
    int kt = (gid >> 10) & 7;
    int nt = (gid >> 13) & 3;
    int nb = gid >> 15;
    const float* s = W + ((size_t)nb * 512 + nt * 128 + c) * 512 + kt * 64 + kc * 8;
    f32x4 a = *(const f32x4*)s;
    f32x4 b = *(const f32x4*)(s + 4);
    ull* d = (ull*)(pk + ((size_t)((nb * 4 + nt) * 8 + kt)) * 16384
                       + c * 128 + ((kc * 16) ^ SWZ8(c)));
    d[0] = pack4(a);
    d[1] = pack4(b);
}

// ---------------- layer GEMMs: 128x128 tile, BK=64, 256 thr = 4 waves (2Mx2N) ----
// Per wave 64x64 out = 4x4 f32x4 acc (64 AGPR). LDS 64 KB -> 2 wgs/CU.
// Schedule (m97 2-phase): stage(kt+1 -> buf^1) issued, compute(buf), syncthreads.

#define GEMM_IDS \
    const int bid = blockIdx.x; \
    const int nb = bid & 7; \
    const int mt = (bid >> 3) & 63; \
    const int nt = bid >> 9; \
    const int t = threadIdx.x; \
    const int lane = t & 63; \
    const int wid = t >> 6; \
    const int wm = wid >> 1, wn = wid & 1; \
    const int l15 = lane & 15, lhi = lane >> 4; \
    const int row0 = mt * 128;

#define COMPUTE(BUF) { \
    _Pragma("unroll") for (int kk = 0; kk < 2; kk++) { \
        bf16x8 af[4], bfr[4]; \
        const int ko = (kk * 32 + lhi * 8) * 2; \
        _Pragma("unroll") for (int m = 0; m < 4; m++) { \
            const int r = wm * 64 + m * 16 + l15; \
            af[m] = *(const bf16x8*)(As[BUF] + r * 128 + (ko ^ SWZ8(r))); } \
        _Pragma("unroll") for (int n = 0; n < 4; n++) { \
            const int c = wn * 64 + n * 16 + l15; \
            bfr[n] = *(const bf16x8*)(Bs[BUF] + c * 128 + (ko ^ SWZ8(c))); } \
        __builtin_amdgcn_s_setprio(1); \
        _Pragma("unroll") for (int m = 0; m < 4; m++) \
            _Pragma("unroll") for (int n = 0; n < 4; n++) \
                acc[m][n] = __builtin_amdgcn_mfma_f32_16x16x32_bf16(af[m], bfr[n], acc[m][n], 0, 0, 0); \
        __builtin_amdgcn_s_setprio(0); } }

#define STAGE_B(BUF, KT) { \
    const unsigned char* src = pkb + (KT) * 16384 + wid * 4096 + lane * 16; \
    unsigned char* dst = Bs[BUF] + wid * 4096; \
    _Pragma("unroll") for (int j = 0; j < 4; j++) \
        gload16(src + j * 1024, dst + j * 1024); }

// ---- layer 1: h = relu(x @ W1^T + b1), x f32 reg-staged to bf16 ----
__global__ __launch_bounds__(256, 2)
void gemm1(const float* __restrict__ X, const unsigned char* __restrict__ PK1,
           const float* __restrict__ B1, unsigned short* __restrict__ H)
{
    __shared__ __align__(16) unsigned char As[2][16384];
    __shared__ __align__(16) unsigned char Bs[2][16384];
    GEMM_IDS
    const int colg0 = nb * 512 + nt * 128;

    float bv[4];
    #pragma unroll
    for (int n = 0; n < 4; n++) bv[n] = B1[colg0 + wn * 64 + n * 16 + l15];

    const unsigned char* pkb = PK1 + ((size_t)((nb * 4 + nt) * 8)) * 16384;

    const int sr = t >> 1;             // staging row 0..127
    const int sck = (t & 1) * 32;      // f32 k offset
    const int sckb = (t & 1) * 64;     // byte k offset

    f32x4 acc[4][4];
    #pragma unroll
    for (int m = 0; m < 4; m++)
        #pragma unroll
        for (int n = 0; n < 4; n++) acc[m][n] = (f32x4)(0.f);

#define STAGE_A1(BUF, KT) { \
    const float* xr = X + (size_t)(row0 + sr) * DIM + nb * 512 + (KT) * 64 + sck; \
    _Pragma("unroll") for (int j = 0; j < 4; j++) { \
        f32x4 a = *(const f32x4*)(xr + j * 8); \
        f32x4 b = *(const f32x4*)(xr + j * 8 + 4); \
        bf16x8 v; ((ull*)&v)[0] = pack4(a); ((ull*)&v)[1] = pack4(b); \
        *(bf16x8*)(As[BUF] + sr * 128 + ((sckb + j * 16) ^ SWZ8(sr))) = v; } }

    STAGE_A1(0, 0)
    STAGE_B(0, 0)
    __syncthreads();
    #pragma unroll
    for (int kt = 0; kt < 8; kt++) {
        const int buf = kt & 1;
        if (kt < 7) { STAGE_A1(buf ^ 1, kt + 1) STAGE_B(buf ^ 1, kt + 1) }
        COMPUTE(buf)
        __syncthreads();
    }

    // epilogue: h = relu(acc + b1) -> H [nb][8192][512] bf16
    #pragma unroll
    for (int n = 0; n < 4; n++) {
        const int cl = nt * 128 + wn * 64 + n * 16 + l15;    // 0..511 in block
        #pragma unroll
        for (int m = 0; m < 4; m++) {
            #pragma unroll
            for (int i = 0; i < 4; i++) {
                float v = acc[m][n][i] + bv[n];
                v = v > 0.f ? v : 0.f;
                const int row = row0 + wm * 64 + m * 16 + lhi * 4 + i;
                H[(size_t)nb * BATCH * 512 + (size_t)row * 512 + cl] = f2bf(v);
            }
        }
    }
#undef STAGE_A1
}

// ---- layer 2: out = relu(h @ W2^T + b2), h bf16 via gload_lds (swizzle-inv src) ----
__global__ __launch_bounds__(256, 2)
void gemm2(const unsigned short* __restrict__ H, const unsigned char* __restrict__ PK2,
           const float* __restrict__ B2, float* __restrict__ Out)
{
    __shared__ __align__(16) unsigned char As[2][16384];
    __shared__ __align__(16) unsigned char Bs[2][16384];
    GEMM_IDS
    const int colg0 = nb * 512 + nt * 128;

    float bv[4];
    #pragma unroll
    for (int n = 0; n < 4; n++) bv[n] = B2[colg0 + wn * 64 + n * 16 + l15];

    const unsigned char* pkb = PK2 + ((size_t)((nb * 4 + nt) * 8)) * 16384;

    // A source: H rows (1024 B stride), pre-inverted swizzle so linear LDS dest
    // yields byte layout r*128 + (k*2 ^ SWZ8(r)).
    const int gb = wid * 64 + lane;          // granule within 256
    const int r0 = gb >> 3;
    const int o0 = (gb & 7) * 16;
    const unsigned char* asrc = (const unsigned char*)H + (size_t)nb * BATCH * 1024
                              + (size_t)(row0 + r0) * 1024 + (o0 ^ SWZ8(r0));

    f32x4 acc[4][4];
    #pragma unroll
    for (int m = 0; m < 4; m++)
        #pragma unroll
        for (int n = 0; n < 4; n++) acc[m][n] = (f32x4)(0.f);

#define STAGE_A2(BUF, KT) { \
    unsigned char* dst = As[BUF] + wid * 1024; \
    _Pragma("unroll") for (int j = 0; j < 4; j++) \
        gload16(asrc + (size_t)j * 32768 + (KT) * 128, dst + j * 4096); }

    STAGE_A2(0, 0)
    STAGE_B(0, 0)
    __syncthreads();
    #pragma unroll
    for (int kt = 0; kt < 8; kt++) {
        const int buf = kt & 1;
        if (kt < 7) { STAGE_A2(buf ^ 1, kt + 1) STAGE_B(buf ^ 1, kt + 1) }
        COMPUTE(buf)
        __syncthreads();
    }

    // epilogue: out = relu(acc + b2), f32
    #pragma unroll
    for (int n = 0; n < 4; n++) {
        const int cg = colg0 + wn * 64 + n * 16 + l15;
        #pragma unroll
        for (int m = 0; m < 4; m++) {
            #pragma unroll
            for (int i = 0; i < 4; i++) {
                float v = acc[m][n][i] + bv[n];
                const int row = row0 + wm * 64 + m * 16 + lhi * 4 + i;
                Out[(size_t)row * DIM + cg] = v > 0.f ? v : 0.f;
            }
        }
    }
#undef STAGE_A2
}

extern "C" void kernel_launch(void* const* d_in, const int* in_sizes, int n_in,
                              void* d_out, int out_size, void* d_ws, size_t ws_size,
                              hipStream_t stream) {
    const float* x  = (const float*)d_in[0];
    const float* W1 = (const float*)d_in[1];
    const float* b1 = (const float*)d_in[2];
    const float* W2 = (const float*)d_in[3];
    const float* b2 = (const float*)d_in[4];
    float* out = (float*)d_out;

    char* ws = (char*)d_ws;
    unsigned char* PK1 = (unsigned char*)ws;                    // 4 MB
    unsigned char* PK2 = (unsigned char*)(ws + (4u << 20));     // 4 MB
    unsigned short* Hb = (unsigned short*)(ws + (8u << 20));    // 64 MB

    pack_w<<<1024, 256, 0, stream>>>(W1, PK1);
    pack_w<<<1024, 256, 0, stream>>>(W2, PK2);

    const int GRID = NB * (BATCH / 128) * 4;    // 8*64*4 = 2048
    gemm1<<<GRID, 256, 0, stream>>>(x, PK1, b1, Hb);
    gemm2<<<GRID, 256, 0, stream>>>(Hb, PK2, b2, out);
}

// Round 14
// 117.488 us; speedup vs baseline: 1.7802x; 1.7802x over previous
//
#include <hip/hip_runtime.h>
#include <hip/hip_bf16.h>

#define NB 8
#define BATCH 8192
#define DIM 4096

typedef __attribute__((ext_vector_type(8))) short bf16x8;
typedef __attribute__((ext_vector_type(4))) float f32x4;
typedef unsigned long long ull;

#define SWZ8(r) (((r) & 7) << 4)

__device__ __forceinline__ unsigned short f2bf(float f) {
    return __builtin_bit_cast(unsigned short, __float2bfloat16(f));
}

__device__ __forceinline__ ull pack4(f32x4 f) {
    return (ull)f2bf(f.x) | ((ull)f2bf(f.y) << 16)
         | ((ull)f2bf(f.z) << 32) | ((ull)f2bf(f.w) << 48);
}

__device__ __forceinline__ void gload16(const void* g, void* l) {
    __builtin_amdgcn_global_load_lds(
        (const __attribute__((address_space(1))) unsigned int*)g,
        (__attribute__((address_space(3))) unsigned int*)l, 16, 0, 0);
}

// ---------------- weight pack (R11 layout) ----------------
// (nb, wid 0..7, kidx 0..15, nf 0..3, lane 0..63) x 8 ushorts, linear.
// Fragment: lane -> row = wid*64 + nf*16 + (lane&15), col = kidx*32 + (lane>>4)*8.
// Per (nb,wid): 32768 ush (64 KB); one kidx slot = 2048 ush = 4 KB (DMA-ready).
__global__ void pack_w(const float* __restrict__ W, unsigned short* __restrict__ pk) {
    int gid = blockIdx.x * 256 + threadIdx.x;        // 262144 total
    int lane = gid & 63;
    int nf   = (gid >> 6) & 3;
    int kidx = (gid >> 8) & 15;
    int wid  = (gid >> 12) & 7;
    int nb   = gid >> 15;
    int row  = wid * 64 + nf * 16 + (lane & 15);
    int col  = kidx * 32 + (lane >> 4) * 8;
    const float* s = W + ((size_t)nb * 512 + row) * 512 + col;
    f32x4 a = *(const f32x4*)s;
    f32x4 b = *(const f32x4*)(s + 4);
    ull* d = (ull*)(pk + (size_t)gid * 8);
    d[0] = pack4(a);
    d[1] = pack4(b);
}

// ---------------- fused 2-layer block-diag MLP ----------------
// wg: 64 batch rows x one full diagonal block (512 cols); 512 thr = 8 waves,
// wave wid owns cols wid*64..+64 (acc 4x4 f32x4 = 64 AGPR).
// W delivery: per-wave PRIVATE 3-slot x 4 KB LDS ring fed by global_load_lds
// (no registers, no barriers). Counted vmcnt(4) per halfstep = 2-halfstep
// prefetch lead (~1200+ cy). ZERO barriers in the 32-halfstep K-stream; only
// 3 total (post-x-stage, h-handoff x2). LDS = 64 KB XH + 96 KB rings = 160 KB.
__global__ __launch_bounds__(512, 2)
void fused_mlp(const float* __restrict__ X,
               const unsigned short* __restrict__ PK1,
               const float* __restrict__ B1,
               const unsigned short* __restrict__ PK2,
               const float* __restrict__ B2,
               float* __restrict__ Out)
{
    __shared__ __align__(16) unsigned char POOL[163840];
    unsigned char* XH = POOL;                    // [64 rows][1024B], SWZ8; x then h
    unsigned char* RING = POOL + 65536;          // [wid][3][4096]

    const int bid = blockIdx.x;
    const int nb = bid & 7;       // XCD-pin heuristic
    const int mt = bid >> 3;      // 0..127

    const int t = threadIdx.x;
    const int lane = t & 63;
    const int wid = t >> 6;       // 0..7 -> col slice wid*64
    const int l15 = lane & 15;
    const int lhi = lane >> 4;

    const int row0 = mt * 64;
    const int wc0  = nb * 512;

    // bias preload (oldest VMEM; consumed in epilogues via counted waits)
    float bv1[4], bv2[4];
    #pragma unroll
    for (int n = 0; n < 4; n++) {
        const int c = wc0 + wid * 64 + n * 16 + l15;
        bv1[n] = B1[c];
        bv2[n] = B2[c];
    }

    // A-read bases: r = m*16+l15; addr(m,kk) = ab[m][kk&1] + (kk>>1)*128
    int ab[4][2];
    #pragma unroll
    for (int m = 0; m < 4; m++) {
        const int r_ = m * 16 + l15;
        #pragma unroll
        for (int p = 0; p < 2; p++)
            ab[m][p] = r_ * 1024 + ((p * 64 + lhi * 16) ^ SWZ8(r_));
    }

    const unsigned short* wp1 = PK1 + (size_t)(nb * 8 + wid) * 32768 + lane * 8;
    const unsigned short* wp2 = PK2 + (size_t)(nb * 8 + wid) * 32768 + lane * 8;
    unsigned char* ring_w = RING + wid * 12288;              // wave-uniform base
    const unsigned char* ring_r = RING + wid * 12288 + lane * 16;  // per-lane read base

    f32x4 acc[4][4];
    #pragma unroll
    for (int m = 0; m < 4; m++)
        #pragma unroll
        for (int n = 0; n < 4; n++)
            acc[m][n] = (f32x4)(0.f);

// issue one 4 KB W slot into ring position POS (4x gload16; dst wave-uniform)
#define ISSUE(POS, WPTR) { \
    _Pragma("unroll") for (int n_ = 0; n_ < 4; n_++) \
        gload16((WPTR) + n_ * 512, ring_w + (POS) * 4096 + n_ * 1024); \
    (WPTR) += 2048; }

// halfstep G (0..31): wait slot G landed, issue slot G+2, ds_read W + A, 16 MFMA
#define STEP_BODY(G) \
    { \
        bf16x8 bfr[4]; \
        _Pragma("unroll") for (int n_ = 0; n_ < 4; n_++) \
            bfr[n_] = *(const bf16x8*)(ring_r + ((G) % 3) * 4096 + n_ * 1024); \
        const int kk_ = (G) & 15; \
        __builtin_amdgcn_s_setprio(1); \
        _Pragma("unroll") for (int m_ = 0; m_ < 4; m_++) { \
            bf16x8 af = *(const bf16x8*)(XH + ab[m_][kk_ & 1] + (kk_ >> 1) * 128); \
            _Pragma("unroll") for (int n_ = 0; n_ < 4; n_++) \
                acc[m_][n_] = __builtin_amdgcn_mfma_f32_16x16x32_bf16(af, bfr[n_], acc[m_][n_], 0, 0, 0); \
        } \
        __builtin_amdgcn_s_setprio(0); \
    }

#define STEP(G, WPTR) { \
    asm volatile("s_waitcnt vmcnt(4)" ::: "memory"); \
    __builtin_amdgcn_sched_barrier(0); \
    ISSUE((G + 2) % 3, WPTR); \
    __builtin_amdgcn_sched_barrier(0); \
    STEP_BODY(G) }

#define STEP_NI(G, VM) { \
    asm volatile("s_waitcnt vmcnt(" #VM ")" ::: "memory"); \
    __builtin_amdgcn_sched_barrier(0); \
    STEP_BODY(G) }

#define BAR() { \
    asm volatile("s_waitcnt lgkmcnt(0)" ::: "memory"); \
    __builtin_amdgcn_s_barrier(); \
    __builtin_amdgcn_sched_barrier(0); }

    // ---- prologue: stage full x tile [64][512] f32 -> bf16 SWZ8 into XH ----
    {
        const int sr = t >> 3;                        // row 0..63
        const int cb = (t & 7) * 128;                 // byte base within row
        const float* xr = X + (size_t)(row0 + sr) * DIM + wc0 + (t & 7) * 64;
        #pragma unroll
        for (int i = 0; i < 8; i++) {
            f32x4 a = *(const f32x4*)(xr + i * 8);
            f32x4 b = *(const f32x4*)(xr + i * 8 + 4);
            bf16x8 v;
            ((ull*)&v)[0] = pack4(a);
            ((ull*)&v)[1] = pack4(b);
            *(bf16x8*)(XH + sr * 1024 + ((cb + i * 16) ^ SWZ8(sr))) = v;
        }
    }
    // seed ring: slots 0,1 (x loads already drained by ds_write data deps)
    ISSUE(0, wp1);
    ISSUE(1, wp1);
    BAR();

    // ================= phase 1: acc = x @ W1^T (no barriers) =================
    STEP(0,  wp1) STEP(1,  wp1) STEP(2,  wp1) STEP(3,  wp1)
    STEP(4,  wp1) STEP(5,  wp1) STEP(6,  wp1) STEP(7,  wp1)
    STEP(8,  wp1) STEP(9,  wp1) STEP(10, wp1) STEP(11, wp1)
    STEP(12, wp1) STEP(13, wp1) STEP(14, wp2) STEP(15, wp2)

    BAR();   // all XH(x) reads retired chip... wg-wide -> safe to overwrite with h

    // ---- h = relu(acc + b1) -> XH (same SWZ8 layout) ----
    #pragma unroll
    for (int n = 0; n < 4; n++) {
        const int c = wid * 64 + n * 16 + l15;
        #pragma unroll
        for (int m = 0; m < 4; m++) {
            #pragma unroll
            for (int rr = 0; rr < 4; rr++) {
                float v = acc[m][n][rr] + bv1[n];
                v = v > 0.f ? v : 0.f;
                const int r = m * 16 + lhi * 4 + rr;
                *(unsigned short*)(XH + r * 1024 + ((c * 2) ^ SWZ8(r))) = f2bf(v);
            }
        }
    }
    BAR();   // h visible

    #pragma unroll
    for (int m = 0; m < 4; m++)
        #pragma unroll
        for (int n = 0; n < 4; n++)
            acc[m][n] = (f32x4)(0.f);

    // ================= phase 2: acc = h @ W2^T (no barriers) =================
    STEP(16, wp2) STEP(17, wp2) STEP(18, wp2) STEP(19, wp2)
    STEP(20, wp2) STEP(21, wp2) STEP(22, wp2) STEP(23, wp2)
    STEP(24, wp2) STEP(25, wp2) STEP(26, wp2) STEP(27, wp2)
    STEP(28, wp2) STEP(29, wp2) STEP_NI(30, 4) STEP_NI(31, 0)

    // ---- epilogue: out = relu(acc + b2), f32 ----
    #pragma unroll
    for (int n = 0; n < 4; n++) {
        const int c = wc0 + wid * 64 + n * 16 + l15;
        #pragma unroll
        for (int m = 0; m < 4; m++) {
            const int rb = row0 + m * 16 + lhi * 4;
            #pragma unroll
            for (int rr = 0; rr < 4; rr++) {
                float v = acc[m][n][rr] + bv2[n];
                Out[(size_t)(rb + rr) * DIM + c] = v > 0.f ? v : 0.f;
            }
        }
    }

#undef ISSUE
#undef STEP_BODY
#undef STEP
#undef STEP_NI
#undef BAR
}

extern "C" void kernel_launch(void* const* d_in, const int* in_sizes, int n_in,
                              void* d_out, int out_size, void* d_ws, size_t ws_size,
                              hipStream_t stream) {
    const float* x  = (const float*)d_in[0];
    const float* W1 = (const float*)d_in[1];
    const float* b1 = (const float*)d_in[2];
    const float* W2 = (const float*)d_in[3];
    const float* b2 = (const float*)d_in[4];
    float* out = (float*)d_out;

    char* ws = (char*)d_ws;
    unsigned short* PK1 = (unsigned short*)ws;                 // 4 MB
    unsigned short* PK2 = (unsigned short*)(ws + (4u << 20));  // 4 MB

    pack_w<<<1024, 256, 0, stream>>>(W1, PK1);
    pack_w<<<1024, 256, 0, stream>>>(W2, PK2);

    const int GRID = NB * (BATCH / 64);     // 1024
    fused_mlp<<<GRID, 512, 0, stream>>>(x, PK1, b1, PK2, b2, out);
}